// Round 3
// baseline (44.188 us; speedup 1.0000x reference)
//
#include <hip/hip_runtime.h>
#include <hip/hip_bf16.h>

constexpr int Bc = 4, Cc = 64, Tc = 16, Nc = 256, Hc = 128, Wc = 128;
constexpr int HW  = Hc * Wc;       // 16384
constexpr int THW = Tc * HW;       // 262144
constexpr int NPTS = Bc * Tc * Nc; // 16384

constexpr int GPB = 16;                         // points per gather block
constexpr int GATHER_BLOCKS = NPTS / GPB;       // 1024
constexpr int MSE_BLOCKS    = 64;
constexpr int NSLICE = 232;                     // 64+60+56+52
constexpr int PAIR_BLOCKS = NSLICE * 2;         // 464

// ws float layout:
//   [0..63]    mse partials (per mse block)
//   [64..527]  se partials  (per pair block)
//   [528..991] cnt partials (as float, per pair block)
//   [1024..]   sel as bf16, NPTS x 64  (2 MB)

typedef short short8 __attribute__((ext_vector_type(8)));
typedef float f32x4  __attribute__((ext_vector_type(4)));

__device__ inline unsigned pack_bf16(float a, float b) {
    __hip_bfloat16 ha = __float2bfloat16(a);
    __hip_bfloat16 hb = __float2bfloat16(b);
    unsigned short ua, ub;
    __builtin_memcpy(&ua, &ha, 2);
    __builtin_memcpy(&ub, &hb, 2);
    return (unsigned)ua | ((unsigned)ub << 16);
}

__global__ __launch_bounds__(256) void k1_gather_mse(
        const float* __restrict__ feat,
        const int*   __restrict__ coord,
        const float* __restrict__ pred,
        const float* __restrict__ tgt,
        float* __restrict__ ws) {
    __shared__ float ls[4];
    int blk = blockIdx.x;
    int t   = threadIdx.x;

    if (blk < GATHER_BLOCKS) {
        int p  = blk * GPB + (t >> 4);  // point id
        int cg = t & 15;                // channel group: channels 4*cg..4*cg+3
        int b  = p >> 12;
        int tt = (p >> 8) & 15;
        int x = coord[2 * p + 0];
        int y = coord[2 * p + 1];
        bool ok = (x >= 0) && (y >= 0);
        float v0 = 0.f, v1 = 0.f, v2 = 0.f, v3 = 0.f;
        if (ok) {
            const float* fb = feat + ((size_t)(b * Cc + cg * 4) * THW
                                      + tt * HW + y * Wc + x);
            v0 = fb[0];
            v1 = fb[THW];
            v2 = fb[2 * THW];
            v3 = fb[3 * THW];
        }
        float sq = v0 * v0 + v1 * v1 + v2 * v2 + v3 * v3;
        #pragma unroll
        for (int o = 8; o; o >>= 1) sq += __shfl_xor(sq, o);  // 16-lane group sum
        float inv = 1.0f / fmaxf(sqrtf(sq), 1e-12f);
        uint2 outv;
        outv.x = pack_bf16(v0 * inv, v1 * inv);
        outv.y = pack_bf16(v2 * inv, v3 * inv);
        uint2* sel2 = (uint2*)(ws + 1024);
        sel2[p * 16 + cg] = outv;
    } else {
        int i = (blk - GATHER_BLOCKS) * 256 + t;
        float4 p4 = ((const float4*)pred)[i];
        float4 q4 = ((const float4*)tgt)[i];
        float dx = p4.x - q4.x, dy = p4.y - q4.y;
        float dz = p4.z - q4.z, dw = p4.w - q4.w;
        float s = dx * dx + dy * dy + dz * dz + dw * dw;
        #pragma unroll
        for (int o = 32; o; o >>= 1) s += __shfl_xor(s, o);
        if ((t & 63) == 0) ls[t >> 6] = s;
        __syncthreads();
        if (t == 0)
            ws[blk - GATHER_BLOCKS] = (ls[0] + ls[1]) + (ls[2] + ls[3]);
    }
}

__global__ __launch_bounds__(512) void k2_pair(
        const int* __restrict__ coord,
        const int* __restrict__ label,
        float* __restrict__ ws) {
    const short8* selb = (const short8*)(ws + 1024); // 8 chunks of 8 bf16 per row

    int blk   = blockIdx.x;
    int slice = blk >> 1;
    int half  = blk & 1;

    int lag, base, thr2;
    if (slice < 64)       { lag = 0; base = 0;   thr2 = 625;  }
    else if (slice < 124) { lag = 1; base = 64;  thr2 = 625;  }
    else if (slice < 180) { lag = 2; base = 124; thr2 = 900;  }
    else                  { lag = 3; base = 180; thr2 = 1225; }
    int idx = slice - base;
    int ns  = Tc - lag;
    int b   = idx / ns;
    int ta  = idx % ns;
    int tb  = ta + lag;
    int pA  = (b * Tc + ta) * Nc;
    int pB  = (b * Tc + tb) * Nc;

    int t    = threadIdx.x;
    int w    = t >> 6;
    int lane = t & 63;
    int lr   = lane & 15;
    int kb   = lane >> 4;   // 0..3

    int rb0 = w * 32;
    int rb1 = w * 32 + 16;

    // A fragments (rows pA+rb+lr, channel chunks kb and 4+kb)
    const short8* arow0 = selb + (size_t)(pA + rb0 + lr) * 8;
    const short8* arow1 = selb + (size_t)(pA + rb1 + lr) * 8;
    short8 a00 = arow0[kb],     a01 = arow0[4 + kb];
    short8 a10 = arow1[kb],     a11 = arow1[4 + kb];

    // per-lane A-side epilogue data: rows rb + kb*4 + i
    int ax0[4], ay0[4], la0[4], ax1[4], ay1[4], la1[4];
    #pragma unroll
    for (int i = 0; i < 4; i++) {
        int r0 = pA + rb0 + kb * 4 + i;
        int r1 = pA + rb1 + kb * 4 + i;
        ax0[i] = coord[2 * r0]; ay0[i] = coord[2 * r0 + 1]; la0[i] = label[r0];
        ax1[i] = coord[2 * r1]; ay1[i] = coord[2 * r1 + 1]; la1[i] = label[r1];
    }

    float se = 0.0f;
    int cnt = 0;

    for (int cb = 0; cb < 8; cb++) {
        int m  = half * 128 + cb * 16;
        int pm = pB + m + lr;
        const short8* brow = selb + (size_t)pm * 8;
        short8 b0 = brow[kb], b1 = brow[4 + kb];
        int bx = coord[2 * pm], by = coord[2 * pm + 1], lb = label[pm];
        bool bok = bx >= 0;

        f32x4 acc0 = {0.f, 0.f, 0.f, 0.f};
        acc0 = __builtin_amdgcn_mfma_f32_16x16x32_bf16(a00, b0, acc0, 0, 0, 0);
        acc0 = __builtin_amdgcn_mfma_f32_16x16x32_bf16(a01, b1, acc0, 0, 0, 0);
        #pragma unroll
        for (int i = 0; i < 4; i++) {
            int ddx = ax0[i] - bx, ddy = ay0[i] - by;
            int dd  = ddx * ddx + ddy * ddy;
            bool cond = (dd < thr2) && (ax0[i] >= 0) && bok;
            float lbl = (la0[i] == lb) ? 1.0f : 0.0f;
            float df  = acc0[i] - lbl;
            df = cond ? df : 0.0f;
            se = fmaf(df, df, se);
            cnt += cond ? 1 : 0;
        }

        f32x4 acc1 = {0.f, 0.f, 0.f, 0.f};
        acc1 = __builtin_amdgcn_mfma_f32_16x16x32_bf16(a10, b0, acc1, 0, 0, 0);
        acc1 = __builtin_amdgcn_mfma_f32_16x16x32_bf16(a11, b1, acc1, 0, 0, 0);
        #pragma unroll
        for (int i = 0; i < 4; i++) {
            int ddx = ax1[i] - bx, ddy = ay1[i] - by;
            int dd  = ddx * ddx + ddy * ddy;
            bool cond = (dd < thr2) && (ax1[i] >= 0) && bok;
            float lbl = (la1[i] == lb) ? 1.0f : 0.0f;
            float df  = acc1[i] - lbl;
            df = cond ? df : 0.0f;
            se = fmaf(df, df, se);
            cnt += cond ? 1 : 0;
        }
    }

    #pragma unroll
    for (int o = 32; o; o >>= 1) {
        se  += __shfl_xor(se, o);
        cnt += __shfl_xor(cnt, o);
    }
    __shared__ float wse[8];
    __shared__ int   wcnt[8];
    if (lane == 0) { wse[w] = se; wcnt[w] = cnt; }
    __syncthreads();
    if (t == 0) {
        float S = 0.0f; int C = 0;
        #pragma unroll
        for (int i = 0; i < 8; i++) { S += wse[i]; C += wcnt[i]; }
        ws[64 + blk]  = S;
        ws[528 + blk] = (float)C;
    }
}

__global__ __launch_bounds__(256) void k3_final(
        const float* __restrict__ ws,
        float* __restrict__ out) {
    int t = threadIdx.x;
    int w = t >> 6, lane = t & 63;

    float ms = (t < 64) ? ws[t] : 0.0f;
    float se4[4] = {0, 0, 0, 0};
    float cn4[4] = {0, 0, 0, 0};
    for (int i = t; i < PAIR_BLOCKS; i += 256) {
        int slice = i >> 1;
        int lg = (slice < 64) ? 0 : (slice < 124) ? 1 : (slice < 180) ? 2 : 3;
        se4[lg] += ws[64 + i];
        cn4[lg] += ws[528 + i];
    }
    #pragma unroll
    for (int o = 32; o; o >>= 1) {
        ms += __shfl_xor(ms, o);
        #pragma unroll
        for (int lg = 0; lg < 4; lg++) {
            se4[lg] += __shfl_xor(se4[lg], o);
            cn4[lg] += __shfl_xor(cn4[lg], o);
        }
    }
    __shared__ float sh[4][9];
    if (lane == 0) {
        sh[w][0] = ms;
        #pragma unroll
        for (int lg = 0; lg < 4; lg++) {
            sh[w][1 + lg] = se4[lg];
            sh[w][5 + lg] = cn4[lg];
        }
    }
    __syncthreads();
    if (t == 0) {
        float mse = 0.0f;
        float se[4] = {0, 0, 0, 0}, cn[4] = {0, 0, 0, 0};
        for (int i = 0; i < 4; i++) {
            mse += sh[i][0];
            for (int lg = 0; lg < 4; lg++) {
                se[lg] += sh[i][1 + lg];
                cn[lg] += sh[i][5 + lg];
            }
        }
        float l = 0.0f;
        for (int lg = 0; lg < 4; lg++)
            l += se[lg] / fmaxf(cn[lg], 1.0f);
        out[0] = mse / 65536.0f + 0.25f * l;
    }
}

extern "C" void kernel_launch(void* const* d_in, const int* in_sizes, int n_in,
                              void* d_out, int out_size, void* d_ws, size_t ws_size,
                              hipStream_t stream) {
    const float* predicts = (const float*)d_in[0];
    const float* feature  = (const float*)d_in[1];
    const int*   coord    = (const int*)d_in[2];
    const float* targets  = (const float*)d_in[3];
    const int*   label    = (const int*)d_in[4];
    float* out = (float*)d_out;
    float* ws  = (float*)d_ws;

    hipLaunchKernelGGL(k1_gather_mse, dim3(GATHER_BLOCKS + MSE_BLOCKS), dim3(256),
                       0, stream, feature, coord, predicts, targets, ws);
    hipLaunchKernelGGL(k2_pair, dim3(PAIR_BLOCKS), dim3(512), 0, stream,
                       coord, label, ws);
    hipLaunchKernelGGL(k3_final, dim3(1), dim3(256), 0, stream, ws, out);
}